// Round 6
// baseline (310.591 us; speedup 1.0000x reference)
//
#include <hip/hip_runtime.h>
#include <hip/hip_bf16.h>
#include <stdint.h>

using f32x4  = __attribute__((ext_vector_type(4))) float;
using bf16x8 = __attribute__((ext_vector_type(8))) __bf16;

__device__ __forceinline__ unsigned short f2bf(float f) {
  union { float f; unsigned u; } x; x.f = f;
  unsigned r = x.u + 0x7fffu + ((x.u >> 16) & 1u);
  return (unsigned short)(r >> 16);
}

__device__ __forceinline__ void gload_lds16(const void* g, void* l) {
  __builtin_amdgcn_global_load_lds((const __attribute__((address_space(1))) void*)g,
                                   (__attribute__((address_space(3))) void*)l, 16, 0, 0);
}

// ---------------- fp32 -> bf16 elementwise ----------------
__global__ __launch_bounds__(256) void f32_to_bf16_k(const float* __restrict__ in,
                                                     unsigned short* __restrict__ out, int n4) {
  int i = blockIdx.x * 256 + threadIdx.x;
  if (i >= n4) return;
  const float4 v = *(const float4*)(in + (size_t)i * 4);
  union { unsigned short s[4]; uint2 u; } p;
  p.s[0] = f2bf(v.x); p.s[1] = f2bf(v.y); p.s[2] = f2bf(v.z); p.s[3] = f2bf(v.w);
  *(uint2*)(out + (size_t)i * 4) = p.u;
}

// ---------------- W[K=1024][N=1024] fp32 -> WT[N][K] bf16 (scaled) ----------------
__global__ __launch_bounds__(256) void prep_wt_k(const float* __restrict__ W,
                                                 unsigned short* __restrict__ WT, float scale) {
  __shared__ float t[32][33];
  const int tx = threadIdx.x & 31, ty = threadIdx.x >> 5;
  const int gx = blockIdx.x * 32, gy = blockIdx.y * 32;
  #pragma unroll
  for (int r = ty; r < 32; r += 8) t[r][tx] = W[(size_t)(gy + r) * 1024 + gx + tx];
  __syncthreads();
  #pragma unroll
  for (int r = ty; r < 32; r += 8)
    WT[(size_t)(gx + r) * 1024 + gy + tx] = f2bf(t[tx][r] * scale);
}

// ---------------- bf16 GEMM: C[M][N] = A[M][K] * BT[N][K]^T + bias ----------------
// EPI 0: bf16 row-major [M][N].
// EPI 1: per-head transposed vT[b][h][d][2048], bf16.
// EPI 2: fp32 row-major [M][N]  (final output buffer is float32).
template<int EPI>
__global__ __launch_bounds__(256) void gemm_bt_k(
    const unsigned short* __restrict__ A,
    const unsigned short* __restrict__ BT,
    const float* __restrict__ bias, float bias_scale,
    void* __restrict__ Cv,
    int M, int N, int K) {
  constexpr int BM = 128, BN = 128, BK = 64;
  __shared__ unsigned short sA[BM * BK];
  __shared__ unsigned short sB[BN * BK];
  const int tid = threadIdx.x;
  const int w = tid >> 6, l = tid & 63, l15 = l & 15, lhi = l >> 4;
  const int wr = w >> 1, wc = w & 1;
  const int m0 = blockIdx.y * BM, n0 = blockIdx.x * BN;

  const f32x4 zero = {0.f, 0.f, 0.f, 0.f};
  f32x4 acc[4][4];
  #pragma unroll
  for (int i = 0; i < 4; i++)
    #pragma unroll
    for (int j = 0; j < 4; j++) acc[i][j] = zero;

  for (int k0 = 0; k0 < K; k0 += BK) {
    __syncthreads();
    // linear LDS dest for global_load_lds; inverse swizzle on SOURCE; swizzle on READ
    #pragma unroll
    for (int i = 0; i < 4; i++) {
      const int p = tid + i * 256;           // physical 16B chunk 0..1023
      const int row = p >> 3;
      const int cl = (p & 7) ^ (row & 7);    // logical k-chunk stored here
      gload_lds16(A + (size_t)(m0 + row) * K + k0 + cl * 8, sA + p * 8);
      gload_lds16(BT + (size_t)(n0 + row) * K + k0 + cl * 8, sB + p * 8);
    }
    __syncthreads();
    #pragma unroll
    for (int kk = 0; kk < 2; kk++) {
      bf16x8 af[4], bfr[4];
      #pragma unroll
      for (int mi = 0; mi < 4; mi++) {
        const int row = wr * 64 + mi * 16 + l15;
        const int c = (kk * 4 + lhi) ^ (row & 7);
        af[mi] = *(const bf16x8*)(sA + row * 64 + c * 8);
      }
      #pragma unroll
      for (int ni = 0; ni < 4; ni++) {
        const int row = wc * 64 + ni * 16 + l15;
        const int c = (kk * 4 + lhi) ^ (row & 7);
        bfr[ni] = *(const bf16x8*)(sB + row * 64 + c * 8);
      }
      #pragma unroll
      for (int mi = 0; mi < 4; mi++)
        #pragma unroll
        for (int ni = 0; ni < 4; ni++)
          acc[mi][ni] = __builtin_amdgcn_mfma_f32_16x16x32_bf16(af[mi], bfr[ni], acc[mi][ni], 0, 0, 0);
    }
  }
  // epilogue: C layout col = lane&15, row = (lane>>4)*4 + reg
  #pragma unroll
  for (int mi = 0; mi < 4; mi++) {
    const int gr = m0 + wr * 64 + mi * 16 + lhi * 4;
    #pragma unroll
    for (int ni = 0; ni < 4; ni++) {
      const int gc = n0 + wc * 64 + ni * 16 + l15;
      const float bs = bias[gc] * bias_scale;
      if constexpr (EPI == 0) {
        unsigned short* C = (unsigned short*)Cv;
        #pragma unroll
        for (int j = 0; j < 4; j++)
          C[(size_t)(gr + j) * N + gc] = f2bf(acc[mi][ni][j] + bs);
      } else if constexpr (EPI == 1) {
        unsigned short* C = (unsigned short*)Cv;
        const int bb = gr >> 11, l2 = gr & 2047;
        const int hh = gc >> 6, dd = gc & 63;
        union { unsigned short s[4]; uint2 u; } pk;
        #pragma unroll
        for (int j = 0; j < 4; j++) pk.s[j] = f2bf(acc[mi][ni][j] + bs);
        *(uint2*)(C + ((size_t)((bb * 16 + hh) * 64 + dd) * 2048 + l2)) = pk.u;
      } else {
        float* C = (float*)Cv;
        #pragma unroll
        for (int j = 0; j < 4; j++)
          C[(size_t)(gr + j) * N + gc] = acc[mi][ni][j] + bs;
      }
    }
  }
}

// ---------------- flash attention ----------------
// 1-D grid of 1024, XCD-swizzled: hb = (id>>7)*8 + (id&7), qt = (id>>3)&15.
// 512 threads = 8 waves sharing one K/V tile; wave w owns q rows qt*128+w*16..+15.
// Scores in log2 domain (log2e/8 folded into Wq,bq) -> exp2f.
// Denominator = ones-column MFMA accumulator oacc[4] (shares bf16 P with O).
__global__ __launch_bounds__(512, 6) void flash_k(
    const unsigned short* __restrict__ qb,   // [B*2048][1024] bf16 (log2e/8 folded)
    const unsigned short* __restrict__ kb,   // [B*2048][1024] bf16
    const unsigned short* __restrict__ vTb,  // [B][16][64][2048] bf16
    const unsigned char* __restrict__ mask,  // [B][2048] (all-false here)
    unsigned short* __restrict__ attnb) {    // [B*2048][1024] bf16
  __shared__ unsigned short sK[2][64 * 64];
  __shared__ unsigned short sV[2][64 * 64];
  __shared__ unsigned short sP[8][16 * 64];
  const int tid = threadIdx.x;
  const int w = tid >> 6, l = tid & 63, l15 = l & 15, lhi = l >> 4;
  const int id = blockIdx.x;
  const int qt = (id >> 3) & 15;
  const int hb = ((id >> 7) << 3) + (id & 7);  // all 16 qt of one (b,h) share an XCD
  const int h = hb & 15, b = hb >> 4;

  const size_t qrow = (size_t)(b * 2048 + qt * 128 + w * 16 + l15);
  const bf16x8 aq0 = *(const bf16x8*)(qb + qrow * 1024 + h * 64 + lhi * 8);
  const bf16x8 aq1 = *(const bf16x8*)(qb + qrow * 1024 + h * 64 + 32 + lhi * 8);

  const f32x4 zero = {0.f, 0.f, 0.f, 0.f};
  f32x4 oacc[5];                 // [0..3] = O, [4] = denominator (ones column)
  #pragma unroll
  for (int d = 0; d < 5; d++) oacc[d] = zero;
  float mrow[4];
  #pragma unroll
  for (int j = 0; j < 4; j++) mrow[j] = 8.0f;  // deferred-max init (log2 units)

  bf16x8 onef;
  #pragma unroll
  for (int i = 0; i < 8; i++) onef[i] = (__bf16)1.0f;

  const unsigned short* kbase = kb + (size_t)(b * 2048) * 1024 + h * 64;
  const unsigned short* vbase = vTb + (size_t)((b * 16 + h) * 64) * 2048;
  const unsigned char* mbase = mask + b * 2048;
  unsigned short* sPw = sP[w];

  // per-thread staging geometry: 512 chunks/tile, thread t stages chunk t
  // (linear LDS dest, inverse-swizzled source)
  const int r0 = tid >> 3, c0s = (tid & 7) ^ (r0 & 7);
  const unsigned short* kp0 = kbase + (size_t)r0 * 1024 + c0s * 8;
  const unsigned short* vp0 = vbase + (size_t)r0 * 2048 + c0s * 8;

  // prologue: stage tile 0 into buffer 0
  gload_lds16(kp0, sK[0] + tid * 8);
  gload_lds16(vp0, sV[0] + tid * 8);
  __syncthreads();

  int cur = 0;
  for (int kt = 0; kt < 32; kt++) {
    // stage next tile into the other buffer (overlaps with all compute below)
    if (kt < 31) {
      const size_t ko = (size_t)(kt + 1) * 64 * 1024;
      const int vo = (kt + 1) * 64;
      gload_lds16(kp0 + ko, sK[cur ^ 1] + tid * 8);
      gload_lds16(vp0 + vo, sV[cur ^ 1] + tid * 8);
    }
    const unsigned short* cK = sK[cur];
    const unsigned short* cV = sV[cur];

    // S = q * k^T : S[16 q][64 k] per wave (log2 domain)
    f32x4 sacc[4];
    #pragma unroll
    for (int n = 0; n < 4; n++) sacc[n] = zero;
    #pragma unroll
    for (int n = 0; n < 4; n++) {
      const int row = n * 16 + l15;
      const int cc0 = lhi ^ (row & 7);
      const int cc1 = (4 + lhi) ^ (row & 7);
      const bf16x8 b0 = *(const bf16x8*)(cK + row * 64 + cc0 * 8);
      const bf16x8 b1 = *(const bf16x8*)(cK + row * 64 + cc1 * 8);
      sacc[n] = __builtin_amdgcn_mfma_f32_16x16x32_bf16(aq0, b0, sacc[n], 0, 0, 0);
      sacc[n] = __builtin_amdgcn_mfma_f32_16x16x32_bf16(aq1, b1, sacc[n], 0, 0, 0);
    }

    // mask: wave-uniform skip (all-false in this problem)
    if (__any(mbase[kt * 64 + l] != 0)) {
      #pragma unroll
      for (int n = 0; n < 4; n++) {
        const float mb = mbase[kt * 64 + n * 16 + l15] ? -1e8f : 0.f;
        #pragma unroll
        for (int j = 0; j < 4; j++) sacc[n][j] += mb;
      }
    }

    // deferred online max: rescale only when a lane sees a new max
    float lmax[4];
    #pragma unroll
    for (int j = 0; j < 4; j++)
      lmax[j] = fmaxf(fmaxf(sacc[0][j], sacc[1][j]), fmaxf(sacc[2][j], sacc[3][j]));
    const bool need = (lmax[0] > mrow[0]) | (lmax[1] > mrow[1]) |
                      (lmax[2] > mrow[2]) | (lmax[3] > mrow[3]);
    if (__any(need)) {
      float tmax[4] = {lmax[0], lmax[1], lmax[2], lmax[3]};
      #pragma unroll
      for (int d = 1; d < 16; d <<= 1)
        #pragma unroll
        for (int j = 0; j < 4; j++) tmax[j] = fmaxf(tmax[j], __shfl_xor(tmax[j], d));
      #pragma unroll
      for (int j = 0; j < 4; j++) {
        const float mnew = fmaxf(mrow[j], tmax[j]);
        const float scl = exp2f(mrow[j] - mnew);
        mrow[j] = mnew;
        #pragma unroll
        for (int d = 0; d < 5; d++) oacc[d][j] *= scl;
      }
    }

    // P = exp2(s - m) -> per-wave LDS (swizzled), bf16
    #pragma unroll
    for (int n = 0; n < 4; n++)
      #pragma unroll
      for (int j = 0; j < 4; j++) {
        const int row = lhi * 4 + j;
        const int col = n * 16 + l15;
        const int cc = (col >> 3) ^ (row & 7);
        *(__bf16*)(sPw + row * 64 + cc * 8 + (col & 7)) =
            (__bf16)exp2f(sacc[n][j] - mrow[j]);
      }
    // intra-wave LDS RAW fence (does NOT drain vmcnt -> staging stays in flight)
    asm volatile("s_waitcnt lgkmcnt(0)" ::: "memory");
    __builtin_amdgcn_sched_barrier(0);
    {
      const int prow = l15;
      const int pc0 = lhi ^ (prow & 7);
      const int pc1 = (4 + lhi) ^ (prow & 7);
      const bf16x8 pa0 = *(const bf16x8*)(sPw + prow * 64 + pc0 * 8);
      const bf16x8 pa1 = *(const bf16x8*)(sPw + prow * 64 + pc1 * 8);
      #pragma unroll
      for (int df = 0; df < 4; df++) {
        const int row = df * 16 + l15;
        const int cc0 = lhi ^ (row & 7);
        const int cc1 = (4 + lhi) ^ (row & 7);
        const bf16x8 v0 = *(const bf16x8*)(cV + row * 64 + cc0 * 8);
        const bf16x8 v1 = *(const bf16x8*)(cV + row * 64 + cc1 * 8);
        oacc[df] = __builtin_amdgcn_mfma_f32_16x16x32_bf16(pa0, v0, oacc[df], 0, 0, 0);
        oacc[df] = __builtin_amdgcn_mfma_f32_16x16x32_bf16(pa1, v1, oacc[df], 0, 0, 0);
      }
      // denominator: ones column (exactly shares bf16 P with the numerator)
      oacc[4] = __builtin_amdgcn_mfma_f32_16x16x32_bf16(pa0, onef, oacc[4], 0, 0, 0);
      oacc[4] = __builtin_amdgcn_mfma_f32_16x16x32_bf16(pa1, onef, oacc[4], 0, 0, 0);
    }
    __syncthreads();   // drains staged loads (vmcnt) + syncs buffer flip
    cur ^= 1;
  }

  // epilogue: O / denom
  float inv[4];
  #pragma unroll
  for (int j = 0; j < 4; j++) inv[j] = 1.0f / oacc[4][j];
  #pragma unroll
  for (int df = 0; df < 4; df++)
    #pragma unroll
    for (int j = 0; j < 4; j++) {
      const size_t r = (size_t)(b * 2048 + qt * 128 + w * 16 + lhi * 4 + j);
      attnb[r * 1024 + h * 64 + df * 16 + l15] = f2bf(oacc[df][j] * inv[j]);
    }
}

// ---------------- launch ----------------
extern "C" void kernel_launch(void* const* d_in, const int* in_sizes, int n_in,
                              void* d_out, int out_size, void* d_ws, size_t ws_size,
                              hipStream_t stream) {
  (void)in_sizes; (void)n_in; (void)out_size; (void)ws_size;
  const float* inp1 = (const float*)d_in[0];
  const float* inp2 = (const float*)d_in[1];
  const unsigned char* mask = (const unsigned char*)d_in[2];
  const float* Wq = (const float*)d_in[3];
  const float* bq = (const float*)d_in[4];
  const float* Wk = (const float*)d_in[5];
  const float* bk = (const float*)d_in[6];
  const float* Wv = (const float*)d_in[7];
  const float* bv = (const float*)d_in[8];
  const float* Wo = (const float*)d_in[9];
  const float* bo = (const float*)d_in[10];
  float* out = (float*)d_out;  // fp32 output (reference output dtype)

  char* p = (char*)d_ws;
  auto alloc = [&](size_t bytes) { char* r = p; p += (bytes + 255) & ~(size_t)255; return r; };
  const size_t ACT = 8192ull * 1024 * 2;   // 16.8 MB bf16 activations
  const size_t WSZ = 1024ull * 1024 * 2;   // 2 MB bf16 weights
  unsigned short* x1b  = (unsigned short*)alloc(ACT);
  unsigned short* x2b  = (unsigned short*)alloc(ACT);
  unsigned short* WqT  = (unsigned short*)alloc(WSZ);
  unsigned short* WkT  = (unsigned short*)alloc(WSZ);
  unsigned short* WvT  = (unsigned short*)alloc(WSZ);
  unsigned short* WoT  = (unsigned short*)alloc(WSZ);
  unsigned short* qbuf = (unsigned short*)alloc(ACT);
  unsigned short* kbuf = (unsigned short*)alloc(ACT);
  unsigned short* vTbf = (unsigned short*)alloc(ACT);
  unsigned short* attb = x1b;  // alias: x1b dead after Q GEMM

  // scores in log2 domain: fold log2(e)/sqrt(HD) = 1.44269504/8 into Wq and bq
  const float QS = 0.18033688011112042f;

  f32_to_bf16_k<<<8192, 256, 0, stream>>>(inp1, x1b, 2097152);
  f32_to_bf16_k<<<8192, 256, 0, stream>>>(inp2, x2b, 2097152);
  dim3 tg(32, 32);
  prep_wt_k<<<tg, 256, 0, stream>>>(Wq, WqT, QS);
  prep_wt_k<<<tg, 256, 0, stream>>>(Wk, WkT, 1.f);
  prep_wt_k<<<tg, 256, 0, stream>>>(Wv, WvT, 1.f);
  prep_wt_k<<<tg, 256, 0, stream>>>(Wo, WoT, 1.f);
  dim3 gg(8, 64);  // (N/128, M/128)
  gemm_bt_k<0><<<gg, 256, 0, stream>>>(x1b, WqT, bq, QS, qbuf, 8192, 1024, 1024);
  gemm_bt_k<0><<<gg, 256, 0, stream>>>(x2b, WkT, bk, 1.f, kbuf, 8192, 1024, 1024);
  gemm_bt_k<1><<<gg, 256, 0, stream>>>(x2b, WvT, bv, 1.f, vTbf, 8192, 1024, 1024);
  flash_k<<<1024, 512, 0, stream>>>(qbuf, kbuf, vTbf, mask, attb);
  gemm_bt_k<2><<<gg, 256, 0, stream>>>(attb, WoT, bo, 1.f, out, 8192, 1024, 1024);
}

// Round 7
// 298.068 us; speedup vs baseline: 1.0420x; 1.0420x over previous
//
#include <hip/hip_runtime.h>
#include <hip/hip_bf16.h>
#include <stdint.h>

using f32x4  = __attribute__((ext_vector_type(4))) float;
using bf16x8 = __attribute__((ext_vector_type(8))) __bf16;

__device__ __forceinline__ unsigned short f2bf(float f) {
  union { float f; unsigned u; } x; x.f = f;
  unsigned r = x.u + 0x7fffu + ((x.u >> 16) & 1u);
  return (unsigned short)(r >> 16);
}

__device__ __forceinline__ void gload_lds16(const void* g, void* l) {
  __builtin_amdgcn_global_load_lds((const __attribute__((address_space(1))) void*)g,
                                   (__attribute__((address_space(3))) void*)l, 16, 0, 0);
}

// ---------------- fp32 -> bf16 elementwise ----------------
__global__ __launch_bounds__(256) void f32_to_bf16_k(const float* __restrict__ in,
                                                     unsigned short* __restrict__ out, int n4) {
  int i = blockIdx.x * 256 + threadIdx.x;
  if (i >= n4) return;
  const float4 v = *(const float4*)(in + (size_t)i * 4);
  union { unsigned short s[4]; uint2 u; } p;
  p.s[0] = f2bf(v.x); p.s[1] = f2bf(v.y); p.s[2] = f2bf(v.z); p.s[3] = f2bf(v.w);
  *(uint2*)(out + (size_t)i * 4) = p.u;
}

// ---------------- W[K=1024][N=1024] fp32 -> WT[N][K] bf16 (scaled) ----------------
__global__ __launch_bounds__(256) void prep_wt_k(const float* __restrict__ W,
                                                 unsigned short* __restrict__ WT, float scale) {
  __shared__ float t[32][33];
  const int tx = threadIdx.x & 31, ty = threadIdx.x >> 5;
  const int gx = blockIdx.x * 32, gy = blockIdx.y * 32;
  #pragma unroll
  for (int r = ty; r < 32; r += 8) t[r][tx] = W[(size_t)(gy + r) * 1024 + gx + tx];
  __syncthreads();
  #pragma unroll
  for (int r = ty; r < 32; r += 8)
    WT[(size_t)(gx + r) * 1024 + gy + tx] = f2bf(t[tx][r] * scale);
}

// ---------------- bf16 GEMM: C[M][N] = A[M][K] * BT[N][K]^T + bias ----------------
// EPI 0: bf16 row-major [M][N].
// EPI 1: per-head transposed vT[b][h][d][2048], bf16.
// EPI 2: fp32 row-major [M][N]  (final output buffer is float32).
template<int EPI>
__global__ __launch_bounds__(256) void gemm_bt_k(
    const unsigned short* __restrict__ A,
    const unsigned short* __restrict__ BT,
    const float* __restrict__ bias, float bias_scale,
    void* __restrict__ Cv,
    int M, int N, int K) {
  constexpr int BM = 128, BN = 128, BK = 64;
  __shared__ unsigned short sA[BM * BK];
  __shared__ unsigned short sB[BN * BK];
  const int tid = threadIdx.x;
  const int w = tid >> 6, l = tid & 63, l15 = l & 15, lhi = l >> 4;
  const int wr = w >> 1, wc = w & 1;
  const int m0 = blockIdx.y * BM, n0 = blockIdx.x * BN;

  const f32x4 zero = {0.f, 0.f, 0.f, 0.f};
  f32x4 acc[4][4];
  #pragma unroll
  for (int i = 0; i < 4; i++)
    #pragma unroll
    for (int j = 0; j < 4; j++) acc[i][j] = zero;

  for (int k0 = 0; k0 < K; k0 += BK) {
    __syncthreads();
    // linear LDS dest for global_load_lds; inverse swizzle on SOURCE; swizzle on READ
    #pragma unroll
    for (int i = 0; i < 4; i++) {
      const int p = tid + i * 256;           // physical 16B chunk 0..1023
      const int row = p >> 3;
      const int cl = (p & 7) ^ (row & 7);    // logical k-chunk stored here
      gload_lds16(A + (size_t)(m0 + row) * K + k0 + cl * 8, sA + p * 8);
      gload_lds16(BT + (size_t)(n0 + row) * K + k0 + cl * 8, sB + p * 8);
    }
    __syncthreads();
    #pragma unroll
    for (int kk = 0; kk < 2; kk++) {
      bf16x8 af[4], bfr[4];
      #pragma unroll
      for (int mi = 0; mi < 4; mi++) {
        const int row = wr * 64 + mi * 16 + l15;
        const int c = (kk * 4 + lhi) ^ (row & 7);
        af[mi] = *(const bf16x8*)(sA + row * 64 + c * 8);
      }
      #pragma unroll
      for (int ni = 0; ni < 4; ni++) {
        const int row = wc * 64 + ni * 16 + l15;
        const int c = (kk * 4 + lhi) ^ (row & 7);
        bfr[ni] = *(const bf16x8*)(sB + row * 64 + c * 8);
      }
      #pragma unroll
      for (int mi = 0; mi < 4; mi++)
        #pragma unroll
        for (int ni = 0; ni < 4; ni++)
          acc[mi][ni] = __builtin_amdgcn_mfma_f32_16x16x32_bf16(af[mi], bfr[ni], acc[mi][ni], 0, 0, 0);
    }
  }
  // epilogue: C layout col = lane&15, row = (lane>>4)*4 + reg
  #pragma unroll
  for (int mi = 0; mi < 4; mi++) {
    const int gr = m0 + wr * 64 + mi * 16 + lhi * 4;
    #pragma unroll
    for (int ni = 0; ni < 4; ni++) {
      const int gc = n0 + wc * 64 + ni * 16 + l15;
      const float bs = bias[gc] * bias_scale;
      if constexpr (EPI == 0) {
        unsigned short* C = (unsigned short*)Cv;
        #pragma unroll
        for (int j = 0; j < 4; j++)
          C[(size_t)(gr + j) * N + gc] = f2bf(acc[mi][ni][j] + bs);
      } else if constexpr (EPI == 1) {
        unsigned short* C = (unsigned short*)Cv;
        const int bb = gr >> 11, l2 = gr & 2047;
        const int hh = gc >> 6, dd = gc & 63;
        union { unsigned short s[4]; uint2 u; } pk;
        #pragma unroll
        for (int j = 0; j < 4; j++) pk.s[j] = f2bf(acc[mi][ni][j] + bs);
        *(uint2*)(C + ((size_t)((bb * 16 + hh) * 64 + dd) * 2048 + l2)) = pk.u;
      } else {
        float* C = (float*)Cv;
        #pragma unroll
        for (int j = 0; j < 4; j++)
          C[(size_t)(gr + j) * N + gc] = acc[mi][ni][j] + bs;
      }
    }
  }
}

// ---------------- flash attention ----------------
// 1-D grid of 2048, XCD-swizzled: id = 256*(hb/8) + 8*qt + (hb&7), hb = h + 16*b.
// 256 threads = 4 waves; wave w owns q rows qt*64 + w*16 .. +15.
// Scores in log2 domain (log2e/8 folded into Wq,bq) -> exp2f.
// P kept as fp32 in LDS (writer: plain b32 stores, no cvt); reader converts
// 16 adjacent-in-register values -> compiler pairs into v_cvt_pk_bf16_f32.
// Denominator = ones-column MFMA accumulator oacc[4] (shares bf16 P with O).
__global__ __launch_bounds__(256, 3) void flash_k(
    const unsigned short* __restrict__ qb,   // [B*2048][1024] bf16 (log2e/8 folded)
    const unsigned short* __restrict__ kb,   // [B*2048][1024] bf16
    const unsigned short* __restrict__ vTb,  // [B][16][64][2048] bf16
    const unsigned char* __restrict__ mask,  // [B][2048] (all-false here)
    unsigned short* __restrict__ attnb) {    // [B*2048][1024] bf16
  __shared__ unsigned short sK[2][64 * 64];
  __shared__ unsigned short sV[2][64 * 64];
  __shared__ float sPf[4][16 * 68];          // fp32 P, row stride 68 (bank spread)
  const int tid = threadIdx.x;
  const int w = tid >> 6, l = tid & 63, l15 = l & 15, lhi = l >> 4;
  const int id = blockIdx.x;
  const int xcd = id & 7;
  const int qt = (id >> 3) & 31;
  const int hb = ((id >> 8) << 3) + xcd;     // all 32 qt of one (b,h) share an XCD
  const int h = hb & 15, b = hb >> 4;

  const size_t qrow = (size_t)(b * 2048 + qt * 64 + w * 16 + l15);
  const bf16x8 aq0 = *(const bf16x8*)(qb + qrow * 1024 + h * 64 + lhi * 8);
  const bf16x8 aq1 = *(const bf16x8*)(qb + qrow * 1024 + h * 64 + 32 + lhi * 8);

  const f32x4 zero = {0.f, 0.f, 0.f, 0.f};
  f32x4 oacc[5];                 // [0..3] = O, [4] = denominator (ones column)
  #pragma unroll
  for (int d = 0; d < 5; d++) oacc[d] = zero;
  float mrow[4];
  #pragma unroll
  for (int j = 0; j < 4; j++) mrow[j] = 8.0f;  // deferred-max init (log2 units)

  bf16x8 onef;
  #pragma unroll
  for (int i = 0; i < 8; i++) onef[i] = (__bf16)1.0f;

  const unsigned short* kbase = kb + (size_t)(b * 2048) * 1024 + h * 64;
  const unsigned short* vbase = vTb + (size_t)((b * 16 + h) * 64) * 2048;
  const unsigned char* mbase = mask + b * 2048;
  float* sPw = sPf[w];

  // per-thread staging geometry (linear LDS dest, inverse-swizzled source)
  const int p0 = tid, p1 = tid + 256;
  const int r0 = p0 >> 3, c0s = (p0 & 7) ^ (r0 & 7);
  const int r1 = p1 >> 3, c1s = (p1 & 7) ^ (r1 & 7);
  const unsigned short* kp0 = kbase + (size_t)r0 * 1024 + c0s * 8;
  const unsigned short* kp1 = kbase + (size_t)r1 * 1024 + c1s * 8;
  const unsigned short* vp0 = vbase + (size_t)r0 * 2048 + c0s * 8;
  const unsigned short* vp1 = vbase + (size_t)r1 * 2048 + c1s * 8;

  // prologue: stage tile 0 into buffer 0
  gload_lds16(kp0, sK[0] + p0 * 8);
  gload_lds16(kp1, sK[0] + p1 * 8);
  gload_lds16(vp0, sV[0] + p0 * 8);
  gload_lds16(vp1, sV[0] + p1 * 8);
  __syncthreads();

  int cur = 0;
  for (int kt = 0; kt < 32; kt++) {
    // stage next tile into the other buffer (overlaps with all compute below)
    if (kt < 31) {
      const size_t ko = (size_t)(kt + 1) * 64 * 1024;
      const int vo = (kt + 1) * 64;
      unsigned short* dK = sK[cur ^ 1];
      unsigned short* dV = sV[cur ^ 1];
      gload_lds16(kp0 + ko, dK + p0 * 8);
      gload_lds16(kp1 + ko, dK + p1 * 8);
      gload_lds16(vp0 + vo, dV + p0 * 8);
      gload_lds16(vp1 + vo, dV + p1 * 8);
    }
    const unsigned short* cK = sK[cur];
    const unsigned short* cV = sV[cur];

    // S = q * k^T : S[16 q][64 k] per wave (log2 domain)
    f32x4 sacc[4];
    #pragma unroll
    for (int n = 0; n < 4; n++) sacc[n] = zero;
    #pragma unroll
    for (int n = 0; n < 4; n++) {
      const int row = n * 16 + l15;
      const int cc0 = lhi ^ (row & 7);
      const int cc1 = (4 + lhi) ^ (row & 7);
      const bf16x8 b0 = *(const bf16x8*)(cK + row * 64 + cc0 * 8);
      const bf16x8 b1 = *(const bf16x8*)(cK + row * 64 + cc1 * 8);
      sacc[n] = __builtin_amdgcn_mfma_f32_16x16x32_bf16(aq0, b0, sacc[n], 0, 0, 0);
      sacc[n] = __builtin_amdgcn_mfma_f32_16x16x32_bf16(aq1, b1, sacc[n], 0, 0, 0);
    }

    // mask: wave-uniform skip (all-false in this problem)
    if (__any(mbase[kt * 64 + l] != 0)) {
      #pragma unroll
      for (int n = 0; n < 4; n++) {
        const float mb = mbase[kt * 64 + n * 16 + l15] ? -1e8f : 0.f;
        #pragma unroll
        for (int j = 0; j < 4; j++) sacc[n][j] += mb;
      }
    }

    // deferred online max: rescale only when a lane sees a new max
    float lmax[4];
    #pragma unroll
    for (int j = 0; j < 4; j++)
      lmax[j] = fmaxf(fmaxf(sacc[0][j], sacc[1][j]), fmaxf(sacc[2][j], sacc[3][j]));
    const bool need = (lmax[0] > mrow[0]) | (lmax[1] > mrow[1]) |
                      (lmax[2] > mrow[2]) | (lmax[3] > mrow[3]);
    if (__any(need)) {
      float tmax[4] = {lmax[0], lmax[1], lmax[2], lmax[3]};
      #pragma unroll
      for (int d = 1; d < 16; d <<= 1)
        #pragma unroll
        for (int j = 0; j < 4; j++) tmax[j] = fmaxf(tmax[j], __shfl_xor(tmax[j], d));
      #pragma unroll
      for (int j = 0; j < 4; j++) {
        const float mnew = fmaxf(mrow[j], tmax[j]);
        const float scl = exp2f(mrow[j] - mnew);
        mrow[j] = mnew;
        #pragma unroll
        for (int d = 0; d < 5; d++) oacc[d][j] *= scl;
      }
    }

    // P = exp2(s - m) -> per-wave LDS as fp32 (no writer-side cvt)
    #pragma unroll
    for (int n = 0; n < 4; n++)
      #pragma unroll
      for (int j = 0; j < 4; j++)
        sPw[(lhi * 4 + j) * 68 + n * 16 + l15] = exp2f(sacc[n][j] - mrow[j]);
    // intra-wave LDS RAW fence (does NOT drain vmcnt -> staging stays in flight)
    asm volatile("s_waitcnt lgkmcnt(0)" ::: "memory");
    __builtin_amdgcn_sched_barrier(0);
    {
      // reader: 16 fp32 -> bf16 (adjacent in registers -> cvt_pk pairing)
      const float* pr = sPw + l15 * 68 + lhi * 8;
      const f32x4 a0 = *(const f32x4*)(pr);
      const f32x4 a1 = *(const f32x4*)(pr + 4);
      const f32x4 a2 = *(const f32x4*)(pr + 32);
      const f32x4 a3 = *(const f32x4*)(pr + 36);
      bf16x8 pa0, pa1;
      #pragma unroll
      for (int i = 0; i < 4; i++) {
        pa0[i]     = (__bf16)a0[i];
        pa0[4 + i] = (__bf16)a1[i];
        pa1[i]     = (__bf16)a2[i];
        pa1[4 + i] = (__bf16)a3[i];
      }
      #pragma unroll
      for (int df = 0; df < 4; df++) {
        const int row = df * 16 + l15;
        const int cc0 = lhi ^ (row & 7);
        const int cc1 = (4 + lhi) ^ (row & 7);
        const bf16x8 v0 = *(const bf16x8*)(cV + row * 64 + cc0 * 8);
        const bf16x8 v1 = *(const bf16x8*)(cV + row * 64 + cc1 * 8);
        oacc[df] = __builtin_amdgcn_mfma_f32_16x16x32_bf16(pa0, v0, oacc[df], 0, 0, 0);
        oacc[df] = __builtin_amdgcn_mfma_f32_16x16x32_bf16(pa1, v1, oacc[df], 0, 0, 0);
      }
      // denominator: ones column (exactly shares bf16 P with the numerator)
      oacc[4] = __builtin_amdgcn_mfma_f32_16x16x32_bf16(pa0, onef, oacc[4], 0, 0, 0);
      oacc[4] = __builtin_amdgcn_mfma_f32_16x16x32_bf16(pa1, onef, oacc[4], 0, 0, 0);
    }
    __syncthreads();   // drains staged loads (vmcnt) + syncs buffer flip
    cur ^= 1;
  }

  // epilogue: O / denom
  float inv[4];
  #pragma unroll
  for (int j = 0; j < 4; j++) inv[j] = 1.0f / oacc[4][j];
  #pragma unroll
  for (int df = 0; df < 4; df++)
    #pragma unroll
    for (int j = 0; j < 4; j++) {
      const size_t r = (size_t)(b * 2048 + qt * 64 + w * 16 + lhi * 4 + j);
      attnb[r * 1024 + h * 64 + df * 16 + l15] = f2bf(oacc[df][j] * inv[j]);
    }
}

// ---------------- launch ----------------
extern "C" void kernel_launch(void* const* d_in, const int* in_sizes, int n_in,
                              void* d_out, int out_size, void* d_ws, size_t ws_size,
                              hipStream_t stream) {
  (void)in_sizes; (void)n_in; (void)out_size; (void)ws_size;
  const float* inp1 = (const float*)d_in[0];
  const float* inp2 = (const float*)d_in[1];
  const unsigned char* mask = (const unsigned char*)d_in[2];
  const float* Wq = (const float*)d_in[3];
  const float* bq = (const float*)d_in[4];
  const float* Wk = (const float*)d_in[5];
  const float* bk = (const float*)d_in[6];
  const float* Wv = (const float*)d_in[7];
  const float* bv = (const float*)d_in[8];
  const float* Wo = (const float*)d_in[9];
  const float* bo = (const float*)d_in[10];
  float* out = (float*)d_out;  // fp32 output (reference output dtype)

  char* p = (char*)d_ws;
  auto alloc = [&](size_t bytes) { char* r = p; p += (bytes + 255) & ~(size_t)255; return r; };
  const size_t ACT = 8192ull * 1024 * 2;   // 16.8 MB bf16 activations
  const size_t WSZ = 1024ull * 1024 * 2;   // 2 MB bf16 weights
  unsigned short* x1b  = (unsigned short*)alloc(ACT);
  unsigned short* x2b  = (unsigned short*)alloc(ACT);
  unsigned short* WqT  = (unsigned short*)alloc(WSZ);
  unsigned short* WkT  = (unsigned short*)alloc(WSZ);
  unsigned short* WvT  = (unsigned short*)alloc(WSZ);
  unsigned short* WoT  = (unsigned short*)alloc(WSZ);
  unsigned short* qbuf = (unsigned short*)alloc(ACT);
  unsigned short* kbuf = (unsigned short*)alloc(ACT);
  unsigned short* vTbf = (unsigned short*)alloc(ACT);
  unsigned short* attb = x1b;  // alias: x1b dead after Q GEMM

  // scores in log2 domain: fold log2(e)/sqrt(HD) = 1.44269504/8 into Wq and bq
  const float QS = 0.18033688011112042f;

  f32_to_bf16_k<<<8192, 256, 0, stream>>>(inp1, x1b, 2097152);
  f32_to_bf16_k<<<8192, 256, 0, stream>>>(inp2, x2b, 2097152);
  dim3 tg(32, 32);
  prep_wt_k<<<tg, 256, 0, stream>>>(Wq, WqT, QS);
  prep_wt_k<<<tg, 256, 0, stream>>>(Wk, WkT, 1.f);
  prep_wt_k<<<tg, 256, 0, stream>>>(Wv, WvT, 1.f);
  prep_wt_k<<<tg, 256, 0, stream>>>(Wo, WoT, 1.f);
  dim3 gg(8, 64);  // (N/128, M/128)
  gemm_bt_k<0><<<gg, 256, 0, stream>>>(x1b, WqT, bq, QS, qbuf, 8192, 1024, 1024);
  gemm_bt_k<0><<<gg, 256, 0, stream>>>(x2b, WkT, bk, 1.f, kbuf, 8192, 1024, 1024);
  gemm_bt_k<1><<<gg, 256, 0, stream>>>(x2b, WvT, bv, 1.f, vTbf, 8192, 1024, 1024);
  flash_k<<<2048, 256, 0, stream>>>(qbuf, kbuf, vTbf, mask, attb);
  gemm_bt_k<2><<<gg, 256, 0, stream>>>(attb, WoT, bo, 1.f, out, 8192, 1024, 1024);
}

// Round 8
// 276.445 us; speedup vs baseline: 1.1235x; 1.0782x over previous
//
#include <hip/hip_runtime.h>
#include <hip/hip_bf16.h>
#include <stdint.h>

using f32x4  = __attribute__((ext_vector_type(4))) float;
using bf16x8 = __attribute__((ext_vector_type(8))) __bf16;

__device__ __forceinline__ unsigned short f2bf(float f) {
  union { float f; unsigned u; } x; x.f = f;
  unsigned r = x.u + 0x7fffu + ((x.u >> 16) & 1u);
  return (unsigned short)(r >> 16);
}

__device__ __forceinline__ void gload_lds16(const void* g, void* l) {
  __builtin_amdgcn_global_load_lds((const __attribute__((address_space(1))) void*)g,
                                   (__attribute__((address_space(3))) void*)l, 16, 0, 0);
}

// ---------------- fp32 -> bf16 elementwise ----------------
__global__ __launch_bounds__(256) void f32_to_bf16_k(const float* __restrict__ in,
                                                     unsigned short* __restrict__ out, int n4) {
  int i = blockIdx.x * 256 + threadIdx.x;
  if (i >= n4) return;
  const float4 v = *(const float4*)(in + (size_t)i * 4);
  union { unsigned short s[4]; uint2 u; } p;
  p.s[0] = f2bf(v.x); p.s[1] = f2bf(v.y); p.s[2] = f2bf(v.z); p.s[3] = f2bf(v.w);
  *(uint2*)(out + (size_t)i * 4) = p.u;
}

// ---------------- W[K=1024][N=1024] fp32 -> WT[N][K] bf16 (scaled) ----------------
__global__ __launch_bounds__(256) void prep_wt_k(const float* __restrict__ W,
                                                 unsigned short* __restrict__ WT, float scale) {
  __shared__ float t[32][33];
  const int tx = threadIdx.x & 31, ty = threadIdx.x >> 5;
  const int gx = blockIdx.x * 32, gy = blockIdx.y * 32;
  #pragma unroll
  for (int r = ty; r < 32; r += 8) t[r][tx] = W[(size_t)(gy + r) * 1024 + gx + tx];
  __syncthreads();
  #pragma unroll
  for (int r = ty; r < 32; r += 8)
    WT[(size_t)(gx + r) * 1024 + gy + tx] = f2bf(t[tx][r] * scale);
}

// ---------------- bf16 GEMM: C[M][N] = A[M][K] * BT[N][K]^T + bias ----------------
// EPI 0: bf16 row-major [M][N].
// EPI 1: per-head transposed vT[b][h][d][2048], bf16.
// EPI 2: fp32 row-major [M][N]  (final output buffer is float32).
template<int EPI>
__global__ __launch_bounds__(256) void gemm_bt_k(
    const unsigned short* __restrict__ A,
    const unsigned short* __restrict__ BT,
    const float* __restrict__ bias, float bias_scale,
    void* __restrict__ Cv,
    int M, int N, int K) {
  constexpr int BM = 128, BN = 128, BK = 64;
  __shared__ unsigned short sA[BM * BK];
  __shared__ unsigned short sB[BN * BK];
  const int tid = threadIdx.x;
  const int w = tid >> 6, l = tid & 63, l15 = l & 15, lhi = l >> 4;
  const int wr = w >> 1, wc = w & 1;
  const int m0 = blockIdx.y * BM, n0 = blockIdx.x * BN;

  const f32x4 zero = {0.f, 0.f, 0.f, 0.f};
  f32x4 acc[4][4];
  #pragma unroll
  for (int i = 0; i < 4; i++)
    #pragma unroll
    for (int j = 0; j < 4; j++) acc[i][j] = zero;

  for (int k0 = 0; k0 < K; k0 += BK) {
    __syncthreads();
    // linear LDS dest for global_load_lds; inverse swizzle on SOURCE; swizzle on READ
    #pragma unroll
    for (int i = 0; i < 4; i++) {
      const int p = tid + i * 256;           // physical 16B chunk 0..1023
      const int row = p >> 3;
      const int cl = (p & 7) ^ (row & 7);    // logical k-chunk stored here
      gload_lds16(A + (size_t)(m0 + row) * K + k0 + cl * 8, sA + p * 8);
      gload_lds16(BT + (size_t)(n0 + row) * K + k0 + cl * 8, sB + p * 8);
    }
    __syncthreads();
    #pragma unroll
    for (int kk = 0; kk < 2; kk++) {
      bf16x8 af[4], bfr[4];
      #pragma unroll
      for (int mi = 0; mi < 4; mi++) {
        const int row = wr * 64 + mi * 16 + l15;
        const int c = (kk * 4 + lhi) ^ (row & 7);
        af[mi] = *(const bf16x8*)(sA + row * 64 + c * 8);
      }
      #pragma unroll
      for (int ni = 0; ni < 4; ni++) {
        const int row = wc * 64 + ni * 16 + l15;
        const int c = (kk * 4 + lhi) ^ (row & 7);
        bfr[ni] = *(const bf16x8*)(sB + row * 64 + c * 8);
      }
      #pragma unroll
      for (int mi = 0; mi < 4; mi++)
        #pragma unroll
        for (int ni = 0; ni < 4; ni++)
          acc[mi][ni] = __builtin_amdgcn_mfma_f32_16x16x32_bf16(af[mi], bfr[ni], acc[mi][ni], 0, 0, 0);
    }
  }
  // epilogue: C layout col = lane&15, row = (lane>>4)*4 + reg
  #pragma unroll
  for (int mi = 0; mi < 4; mi++) {
    const int gr = m0 + wr * 64 + mi * 16 + lhi * 4;
    #pragma unroll
    for (int ni = 0; ni < 4; ni++) {
      const int gc = n0 + wc * 64 + ni * 16 + l15;
      const float bs = bias[gc] * bias_scale;
      if constexpr (EPI == 0) {
        unsigned short* C = (unsigned short*)Cv;
        #pragma unroll
        for (int j = 0; j < 4; j++)
          C[(size_t)(gr + j) * N + gc] = f2bf(acc[mi][ni][j] + bs);
      } else if constexpr (EPI == 1) {
        unsigned short* C = (unsigned short*)Cv;
        const int bb = gr >> 11, l2 = gr & 2047;
        const int hh = gc >> 6, dd = gc & 63;
        union { unsigned short s[4]; uint2 u; } pk;
        #pragma unroll
        for (int j = 0; j < 4; j++) pk.s[j] = f2bf(acc[mi][ni][j] + bs);
        *(uint2*)(C + ((size_t)((bb * 16 + hh) * 64 + dd) * 2048 + l2)) = pk.u;
      } else {
        float* C = (float*)Cv;
        #pragma unroll
        for (int j = 0; j < 4; j++)
          C[(size_t)(gr + j) * N + gc] = acc[mi][ni][j] + bs;
      }
    }
  }
}

// ---------------- flash attention (Q-double) ----------------
// 1-D grid of 1024, XCD-swizzled: xcd=id&7, qt=(id>>3)&15, hb=((id>>7)<<3)+xcd.
// 256 threads = 4 waves; wave w owns q rows qt*128 + w*16 (+0 and +64).
// K/V fragments are shared between the two q-groups of a wave.
// Scores in log2 domain (log2e/8 folded into Wq,bq) -> exp2f.
// Denominator = ones-column MFMA accumulator [4] (shares bf16 P with O).
__global__ __launch_bounds__(256, 3) void flash_k(
    const unsigned short* __restrict__ qb,   // [B*2048][1024] bf16 (log2e/8 folded)
    const unsigned short* __restrict__ kb,   // [B*2048][1024] bf16
    const unsigned short* __restrict__ vTb,  // [B][16][64][2048] bf16
    const unsigned char* __restrict__ mask,  // [B][2048] (all-false here)
    unsigned short* __restrict__ attnb) {    // [B*2048][1024] bf16
  __shared__ unsigned short sK[2][64 * 64];
  __shared__ unsigned short sV[2][64 * 64];
  __shared__ unsigned short sP[4][2][16 * 64];
  const int tid = threadIdx.x;
  const int w = tid >> 6, l = tid & 63, l15 = l & 15, lhi = l >> 4;
  const int id = blockIdx.x;
  const int xcd = id & 7;
  const int qt = (id >> 3) & 15;
  const int hb = ((id >> 7) << 3) + xcd;     // all 16 qt of one (b,h) share an XCD
  const int h = hb & 15, b = hb >> 4;

  const size_t qrowA = (size_t)(b * 2048 + qt * 128 + w * 16 + l15);
  const size_t qrowB = qrowA + 64;
  const bf16x8 aqA0 = *(const bf16x8*)(qb + qrowA * 1024 + h * 64 + lhi * 8);
  const bf16x8 aqA1 = *(const bf16x8*)(qb + qrowA * 1024 + h * 64 + 32 + lhi * 8);
  const bf16x8 aqB0 = *(const bf16x8*)(qb + qrowB * 1024 + h * 64 + lhi * 8);
  const bf16x8 aqB1 = *(const bf16x8*)(qb + qrowB * 1024 + h * 64 + 32 + lhi * 8);

  const f32x4 zero = {0.f, 0.f, 0.f, 0.f};
  f32x4 oaccA[5], oaccB[5];      // [0..3] = O, [4] = denominator (ones column)
  #pragma unroll
  for (int d = 0; d < 5; d++) { oaccA[d] = zero; oaccB[d] = zero; }
  float mrowA[4], mrowB[4];
  #pragma unroll
  for (int j = 0; j < 4; j++) { mrowA[j] = 8.0f; mrowB[j] = 8.0f; }  // log2 units

  bf16x8 onef;
  #pragma unroll
  for (int i = 0; i < 8; i++) onef[i] = (__bf16)1.0f;

  const unsigned short* kbase = kb + (size_t)(b * 2048) * 1024 + h * 64;
  const unsigned short* vbase = vTb + (size_t)((b * 16 + h) * 64) * 2048;
  const unsigned char* mbase = mask + b * 2048;
  unsigned short* sPA = sP[w][0];
  unsigned short* sPB = sP[w][1];

  // block mask pre-scan (mask is all-false -> uniform skip of per-iter handling)
  bool anym_lane = false;
  for (int i = l; i < 2048; i += 64) anym_lane |= (mbase[i] != 0);
  const bool anym = __any(anym_lane);

  // per-thread staging geometry (linear LDS dest, inverse-swizzled source)
  const int p0 = tid, p1 = tid + 256;
  const int r0 = p0 >> 3, c0s = (p0 & 7) ^ (r0 & 7);
  const int r1 = p1 >> 3, c1s = (p1 & 7) ^ (r1 & 7);
  const unsigned short* kp0 = kbase + (size_t)r0 * 1024 + c0s * 8;
  const unsigned short* kp1 = kbase + (size_t)r1 * 1024 + c1s * 8;
  const unsigned short* vp0 = vbase + (size_t)r0 * 2048 + c0s * 8;
  const unsigned short* vp1 = vbase + (size_t)r1 * 2048 + c1s * 8;

  // prologue: stage tile 0 into buffer 0
  gload_lds16(kp0, sK[0] + p0 * 8);
  gload_lds16(kp1, sK[0] + p1 * 8);
  gload_lds16(vp0, sV[0] + p0 * 8);
  gload_lds16(vp1, sV[0] + p1 * 8);
  __syncthreads();

  int cur = 0;
  for (int kt = 0; kt < 32; kt++) {
    // stage next tile into the other buffer (overlaps with all compute below)
    if (kt < 31) {
      const size_t ko = (size_t)(kt + 1) * 64 * 1024;
      const int vo = (kt + 1) * 64;
      unsigned short* dK = sK[cur ^ 1];
      unsigned short* dV = sV[cur ^ 1];
      gload_lds16(kp0 + ko, dK + p0 * 8);
      gload_lds16(kp1 + ko, dK + p1 * 8);
      gload_lds16(vp0 + vo, dV + p0 * 8);
      gload_lds16(vp1 + vo, dV + p1 * 8);
    }
    const unsigned short* cK = sK[cur];
    const unsigned short* cV = sV[cur];

    // S = q * k^T for both q-groups; K fragments shared
    f32x4 sA[4], sB[4];
    #pragma unroll
    for (int n = 0; n < 4; n++) { sA[n] = zero; sB[n] = zero; }
    #pragma unroll
    for (int n = 0; n < 4; n++) {
      const int row = n * 16 + l15;
      const int cc0 = lhi ^ (row & 7);
      const int cc1 = (4 + lhi) ^ (row & 7);
      const bf16x8 k0 = *(const bf16x8*)(cK + row * 64 + cc0 * 8);
      const bf16x8 k1 = *(const bf16x8*)(cK + row * 64 + cc1 * 8);
      sA[n] = __builtin_amdgcn_mfma_f32_16x16x32_bf16(aqA0, k0, sA[n], 0, 0, 0);
      sA[n] = __builtin_amdgcn_mfma_f32_16x16x32_bf16(aqA1, k1, sA[n], 0, 0, 0);
      sB[n] = __builtin_amdgcn_mfma_f32_16x16x32_bf16(aqB0, k0, sB[n], 0, 0, 0);
      sB[n] = __builtin_amdgcn_mfma_f32_16x16x32_bf16(aqB1, k1, sB[n], 0, 0, 0);
    }

    // mask handling (uniform skip; data here is all-false)
    if (anym) {
      #pragma unroll
      for (int n = 0; n < 4; n++) {
        const float mb = mbase[kt * 64 + n * 16 + l15] ? -1e8f : 0.f;
        #pragma unroll
        for (int j = 0; j < 4; j++) { sA[n][j] += mb; sB[n][j] += mb; }
      }
    }

    // deferred online max per group
    {
      float lmax[4];
      #pragma unroll
      for (int j = 0; j < 4; j++)
        lmax[j] = fmaxf(fmaxf(sA[0][j], sA[1][j]), fmaxf(sA[2][j], sA[3][j]));
      const bool need = (lmax[0] > mrowA[0]) | (lmax[1] > mrowA[1]) |
                        (lmax[2] > mrowA[2]) | (lmax[3] > mrowA[3]);
      if (__any(need)) {
        float tmax[4] = {lmax[0], lmax[1], lmax[2], lmax[3]};
        #pragma unroll
        for (int d = 1; d < 16; d <<= 1)
          #pragma unroll
          for (int j = 0; j < 4; j++) tmax[j] = fmaxf(tmax[j], __shfl_xor(tmax[j], d));
        #pragma unroll
        for (int j = 0; j < 4; j++) {
          const float mnew = fmaxf(mrowA[j], tmax[j]);
          const float scl = exp2f(mrowA[j] - mnew);
          mrowA[j] = mnew;
          #pragma unroll
          for (int d = 0; d < 5; d++) oaccA[d][j] *= scl;
        }
      }
    }
    {
      float lmax[4];
      #pragma unroll
      for (int j = 0; j < 4; j++)
        lmax[j] = fmaxf(fmaxf(sB[0][j], sB[1][j]), fmaxf(sB[2][j], sB[3][j]));
      const bool need = (lmax[0] > mrowB[0]) | (lmax[1] > mrowB[1]) |
                        (lmax[2] > mrowB[2]) | (lmax[3] > mrowB[3]);
      if (__any(need)) {
        float tmax[4] = {lmax[0], lmax[1], lmax[2], lmax[3]};
        #pragma unroll
        for (int d = 1; d < 16; d <<= 1)
          #pragma unroll
          for (int j = 0; j < 4; j++) tmax[j] = fmaxf(tmax[j], __shfl_xor(tmax[j], d));
        #pragma unroll
        for (int j = 0; j < 4; j++) {
          const float mnew = fmaxf(mrowB[j], tmax[j]);
          const float scl = exp2f(mrowB[j] - mnew);
          mrowB[j] = mnew;
          #pragma unroll
          for (int d = 0; d < 5; d++) oaccB[d][j] *= scl;
        }
      }
    }

    // P = exp2(s - m) -> per-wave LDS (swizzled), bf16, both groups
    #pragma unroll
    for (int n = 0; n < 4; n++)
      #pragma unroll
      for (int j = 0; j < 4; j++) {
        const int row = lhi * 4 + j;
        const int col = n * 16 + l15;
        const int cc = (col >> 3) ^ (row & 7);
        *(__bf16*)(sPA + row * 64 + cc * 8 + (col & 7)) = (__bf16)exp2f(sA[n][j] - mrowA[j]);
        *(__bf16*)(sPB + row * 64 + cc * 8 + (col & 7)) = (__bf16)exp2f(sB[n][j] - mrowB[j]);
      }
    // intra-wave LDS RAW fence (does NOT drain vmcnt -> staging stays in flight)
    asm volatile("s_waitcnt lgkmcnt(0)" ::: "memory");
    __builtin_amdgcn_sched_barrier(0);
    {
      const int prow = l15;
      const int pc0 = lhi ^ (prow & 7);
      const int pc1 = (4 + lhi) ^ (prow & 7);
      const bf16x8 paA0 = *(const bf16x8*)(sPA + prow * 64 + pc0 * 8);
      const bf16x8 paA1 = *(const bf16x8*)(sPA + prow * 64 + pc1 * 8);
      const bf16x8 paB0 = *(const bf16x8*)(sPB + prow * 64 + pc0 * 8);
      const bf16x8 paB1 = *(const bf16x8*)(sPB + prow * 64 + pc1 * 8);
      #pragma unroll
      for (int df = 0; df < 4; df++) {
        const int row = df * 16 + l15;
        const int cc0 = lhi ^ (row & 7);
        const int cc1 = (4 + lhi) ^ (row & 7);
        const bf16x8 v0 = *(const bf16x8*)(cV + row * 64 + cc0 * 8);
        const bf16x8 v1 = *(const bf16x8*)(cV + row * 64 + cc1 * 8);
        oaccA[df] = __builtin_amdgcn_mfma_f32_16x16x32_bf16(paA0, v0, oaccA[df], 0, 0, 0);
        oaccA[df] = __builtin_amdgcn_mfma_f32_16x16x32_bf16(paA1, v1, oaccA[df], 0, 0, 0);
        oaccB[df] = __builtin_amdgcn_mfma_f32_16x16x32_bf16(paB0, v0, oaccB[df], 0, 0, 0);
        oaccB[df] = __builtin_amdgcn_mfma_f32_16x16x32_bf16(paB1, v1, oaccB[df], 0, 0, 0);
      }
      // denominators: ones column (exactly shares bf16 P with the numerator)
      oaccA[4] = __builtin_amdgcn_mfma_f32_16x16x32_bf16(paA0, onef, oaccA[4], 0, 0, 0);
      oaccA[4] = __builtin_amdgcn_mfma_f32_16x16x32_bf16(paA1, onef, oaccA[4], 0, 0, 0);
      oaccB[4] = __builtin_amdgcn_mfma_f32_16x16x32_bf16(paB0, onef, oaccB[4], 0, 0, 0);
      oaccB[4] = __builtin_amdgcn_mfma_f32_16x16x32_bf16(paB1, onef, oaccB[4], 0, 0, 0);
    }
    __syncthreads();   // drains staged loads (vmcnt) + syncs buffer flip
    cur ^= 1;
  }

  // epilogue: O / denom, both groups
  float invA[4], invB[4];
  #pragma unroll
  for (int j = 0; j < 4; j++) { invA[j] = 1.0f / oaccA[4][j]; invB[j] = 1.0f / oaccB[4][j]; }
  #pragma unroll
  for (int df = 0; df < 4; df++)
    #pragma unroll
    for (int j = 0; j < 4; j++) {
      const size_t rA = (size_t)(b * 2048 + qt * 128 + w * 16 + lhi * 4 + j);
      attnb[rA * 1024 + h * 64 + df * 16 + l15] = f2bf(oaccA[df][j] * invA[j]);
      attnb[(rA + 64) * 1024 + h * 64 + df * 16 + l15] = f2bf(oaccB[df][j] * invB[j]);
    }
}

// ---------------- launch ----------------
extern "C" void kernel_launch(void* const* d_in, const int* in_sizes, int n_in,
                              void* d_out, int out_size, void* d_ws, size_t ws_size,
                              hipStream_t stream) {
  (void)in_sizes; (void)n_in; (void)out_size; (void)ws_size;
  const float* inp1 = (const float*)d_in[0];
  const float* inp2 = (const float*)d_in[1];
  const unsigned char* mask = (const unsigned char*)d_in[2];
  const float* Wq = (const float*)d_in[3];
  const float* bq = (const float*)d_in[4];
  const float* Wk = (const float*)d_in[5];
  const float* bk = (const float*)d_in[6];
  const float* Wv = (const float*)d_in[7];
  const float* bv = (const float*)d_in[8];
  const float* Wo = (const float*)d_in[9];
  const float* bo = (const float*)d_in[10];
  float* out = (float*)d_out;  // fp32 output (reference output dtype)

  char* p = (char*)d_ws;
  auto alloc = [&](size_t bytes) { char* r = p; p += (bytes + 255) & ~(size_t)255; return r; };
  const size_t ACT = 8192ull * 1024 * 2;   // 16.8 MB bf16 activations
  const size_t WSZ = 1024ull * 1024 * 2;   // 2 MB bf16 weights
  unsigned short* x1b  = (unsigned short*)alloc(ACT);
  unsigned short* x2b  = (unsigned short*)alloc(ACT);
  unsigned short* WqT  = (unsigned short*)alloc(WSZ);
  unsigned short* WkT  = (unsigned short*)alloc(WSZ);
  unsigned short* WvT  = (unsigned short*)alloc(WSZ);
  unsigned short* WoT  = (unsigned short*)alloc(WSZ);
  unsigned short* qbuf = (unsigned short*)alloc(ACT);
  unsigned short* kbuf = (unsigned short*)alloc(ACT);
  unsigned short* vTbf = (unsigned short*)alloc(ACT);
  unsigned short* attb = x1b;  // alias: x1b dead after Q GEMM

  // scores in log2 domain: fold log2(e)/sqrt(HD) = 1.44269504/8 into Wq and bq
  const float QS = 0.18033688011112042f;

  f32_to_bf16_k<<<8192, 256, 0, stream>>>(inp1, x1b, 2097152);
  f32_to_bf16_k<<<8192, 256, 0, stream>>>(inp2, x2b, 2097152);
  dim3 tg(32, 32);
  prep_wt_k<<<tg, 256, 0, stream>>>(Wq, WqT, QS);
  prep_wt_k<<<tg, 256, 0, stream>>>(Wk, WkT, 1.f);
  prep_wt_k<<<tg, 256, 0, stream>>>(Wv, WvT, 1.f);
  prep_wt_k<<<tg, 256, 0, stream>>>(Wo, WoT, 1.f);
  dim3 gg(8, 64);  // (N/128, M/128)
  gemm_bt_k<0><<<gg, 256, 0, stream>>>(x1b, WqT, bq, QS, qbuf, 8192, 1024, 1024);
  gemm_bt_k<0><<<gg, 256, 0, stream>>>(x2b, WkT, bk, 1.f, kbuf, 8192, 1024, 1024);
  gemm_bt_k<1><<<gg, 256, 0, stream>>>(x2b, WvT, bv, 1.f, vTbf, 8192, 1024, 1024);
  flash_k<<<1024, 256, 0, stream>>>(qbuf, kbuf, vTbf, mask, attb);
  gemm_bt_k<2><<<gg, 256, 0, stream>>>(attb, WoT, bo, 1.f, out, 8192, 1024, 1024);
}